// Round 6
// baseline (523.634 us; speedup 1.0000x reference)
//
#include <hip/hip_runtime.h>

// GCN + low-rank global attention (LRGA), N=100k, E=1.6M, D=128, K=64.
// R1: k_out -> bf16 MFMA with folded Weff.
// R2: k_gemm1 -> split-bf16 (hi/lo) MFMA 3-pass.
// R3: k_red -> atomic-free two-stage MFMA reduction.
// R4: FAILED (fused split = VALU-bound; weight hoist = occupancy loss). Reverted.
// R5: register double-buffer in gemm1 = null (compiler already schedules).
// R6: k_scatter -> XCD-sharded (WRITE_SIZE was 102MB = 8x line duplication across
//     non-coherent per-XCD L2s); k_gemm1 grid swizzled so all 3 colblks of a row
//     tile land on the same XCD (A fetched into 1 L2 instead of 3).
#define DIN   128
#define DOUT  128
#define KR    64
#define TCOLS 256   // 4*K
#define WCOLS 384   // DOUT + TCOLS
#define P_RED 1024  // stage-1 partial blocks
#define PSTR  4224  // 4096 VtZ + 128 colsum

typedef unsigned short ushort_t;
typedef __attribute__((ext_vector_type(8))) short bf16x8;
typedef __attribute__((ext_vector_type(4))) float f32x4;

__device__ __forceinline__ float bf2f(unsigned short u) {
  return __uint_as_float(((unsigned int)u) << 16);
}
__device__ __forceinline__ unsigned short f2bf(float f) {
  unsigned int b = __float_as_uint(f);
  b = b + 0x7FFFu + ((b >> 16) & 1u);
  return (unsigned short)(b >> 16);
}

// ---------------------------------------------------------------- init
__global__ __launch_bounds__(256) void k_init(int* __restrict__ degc, float* __restrict__ VtZ,
                                              float* __restrict__ colsum, int N) {
  int i = blockIdx.x * 256 + threadIdx.x;
  if (i < N) degc[i] = 1;            // self-loop gives deg >= 1
  if (i < 4096) VtZ[i] = 0.f;
  if (i < 128) colsum[i] = 0.f;
}

// ---------------------------------------------------------------- degree (in-degree via dst row)
__global__ __launch_bounds__(256) void k_deg(const int* __restrict__ ei, int* __restrict__ degc, int E) {
  int e = blockIdx.x * 256 + threadIdx.x;
  if (e < E) atomicAdd(&degc[ei[E + e]], 1);
}

// ---------------------------------------------------------------- x -> bf16 hi/lo split (for MFMA)
__global__ __launch_bounds__(256) void k_split(const float* __restrict__ x,
                                               ushort_t* __restrict__ xh, ushort_t* __restrict__ xl4,
                                               int total4) {
  int i = blockIdx.x * 256 + threadIdx.x;
  int stride = gridDim.x * 256;
  for (; i < total4; i += stride) {
    float4 v = ((const float4*)x)[i];
    ushort4 h, l;
    h.x = f2bf(v.x); h.y = f2bf(v.y); h.z = f2bf(v.z); h.w = f2bf(v.w);
    l.x = f2bf(v.x - bf2f(h.x)); l.y = f2bf(v.y - bf2f(h.y));
    l.z = f2bf(v.z - bf2f(h.z)); l.w = f2bf(v.w - bf2f(h.w));
    ((ushort4*)xh)[i] = h;
    ((ushort4*)xl4)[i] = l;
  }
}

// ---------------------------------------------------------------- weights -> K-major bf16 hi/lo
__global__ __launch_bounds__(128) void k_wprep(const float* __restrict__ Wg, const float* __restrict__ Wa,
                                               ushort_t* __restrict__ whT, ushort_t* __restrict__ wlT) {
  int n = blockIdx.x;      // 0..383
  int k = threadIdx.x;     // 0..127
  float v = (n < DOUT) ? Wg[(size_t)k * DOUT + n] : Wa[(size_t)k * TCOLS + (n - DOUT)];
  ushort_t h = f2bf(v);
  whT[(size_t)n * DIN + k] = h;
  wlT[(size_t)n * DIN + k] = f2bf(v - bf2f(h));
}

// ---------------------------------------------------------------- hierarchical scan, stage 1
__global__ __launch_bounds__(256) void k_scan1(const int* __restrict__ degc, int* __restrict__ offs,
                                               int* __restrict__ bsums, int N) {
  __shared__ int s[256];
  int tid = threadIdx.x;
  int base = blockIdx.x * 1024 + tid * 4;
  int c[4], e[4];
#pragma unroll
  for (int q = 0; q < 4; ++q) c[q] = (base + q < N) ? (degc[base + q] - 1) : 0;
  e[0] = 0; e[1] = c[0]; e[2] = e[1] + c[1]; e[3] = e[2] + c[2];
  int tsum = e[3] + c[3];
  s[tid] = tsum; __syncthreads();
  for (int off = 1; off < 256; off <<= 1) {
    int v = (tid >= off) ? s[tid - off] : 0;
    __syncthreads();
    s[tid] += v;
    __syncthreads();
  }
  int tb = s[tid] - tsum;
#pragma unroll
  for (int q = 0; q < 4; ++q) if (base + q < N) offs[base + q] = tb + e[q];
  if (tid == 255) bsums[blockIdx.x] = s[255];
}

// stage 2: exclusive scan of block sums (NBLK <= 128)
__global__ __launch_bounds__(128) void k_scan2(const int* __restrict__ bsums, int* __restrict__ boff,
                                               int* __restrict__ offs, int NBLK, int N) {
  __shared__ int s[128];
  int tid = threadIdx.x;
  int v = (tid < NBLK) ? bsums[tid] : 0;
  s[tid] = v; __syncthreads();
  for (int off = 1; off < 128; off <<= 1) {
    int u = (tid >= off) ? s[tid - off] : 0;
    __syncthreads();
    s[tid] += u;
    __syncthreads();
  }
  boff[tid] = s[tid] - v;
  if (tid == 127) offs[N] = s[127];   // total = E
}

// stage 3: add block offsets; dinv = rsqrt(deg); cursor = 0
__global__ __launch_bounds__(256) void k_scan3(int* __restrict__ offs, const int* __restrict__ boff,
                                               const int* __restrict__ degc, float* __restrict__ dinv,
                                               int* __restrict__ cursor, int N) {
  int i = blockIdx.x * 256 + threadIdx.x;
  if (i < N) {
    offs[i] += boff[i >> 10];
    dinv[i] = rsqrtf((float)degc[i]);
    cursor[i] = 0;
  }
}

// ---------------------------------------------------------------- CSR scatter, XCD-sharded.
// Shard s = blockIdx%8 (round-robin block->XCD) handles dst in [s*shardN, min(..,N)).
// All writes to a csr slice come from one XCD's L2 -> full-line writebacks (no 8x
// masked-writeback amplification). dst stream is read 8x but coalesced + LLC-cached.
__global__ __launch_bounds__(256) void k_scatter(const int* __restrict__ ei, const int* __restrict__ offs,
                                                 int* __restrict__ cursor, const float* __restrict__ dinv,
                                                 int2* __restrict__ csr, int E, int N, int shardN) {
  int shard = blockIdx.x & 7;
  int lo = shard * shardN;
  int hi = min(lo + shardN, N);
  int e = (blockIdx.x >> 3) * 256 + threadIdx.x;
  int stride = (gridDim.x >> 3) * 256;
  for (; e < E; e += stride) {
    int d = ei[E + e];
    if (d >= lo && d < hi) {
      int s = ei[e];
      int pos = atomicAdd(&cursor[d], 1);
      int2 q;
      q.x = s;
      q.y = __float_as_int(dinv[s] * dinv[d]);
      csr[offs[d] + pos] = q;
    }
  }
}

// ---------------------------------------------------------------- fused GEMM via MFMA (split bf16, 3-pass)
// R6: 1-D swizzled grid: the 3 colblks of one row-tile share blockIdx%8 -> same XCD,
// so the A tile (xh/xlo rows) is fetched into one L2 and reused by all 3.
#define LOADK(S, AH, AL, BH, BL)                                              \
  {                                                                           \
    int k0_ = (S) * 32 + lk;                                                  \
    _Pragma("unroll") for (int m_ = 0; m_ < 4; ++m_) {                        \
      AH[m_] = *(const bf16x8*)&xh[(size_t)rows[m_] * DIN + k0_];             \
      AL[m_] = *(const bf16x8*)&xlo[(size_t)rows[m_] * DIN + k0_];            \
    }                                                                         \
    _Pragma("unroll") for (int n_ = 0; n_ < 4; ++n_) {                        \
      int gc_ = gcb + n_ * 16 + lr;                                           \
      BH[n_] = *(const bf16x8*)&whT[(size_t)gc_ * DIN + k0_];                 \
      BL[n_] = *(const bf16x8*)&wlT[(size_t)gc_ * DIN + k0_];                 \
    }                                                                         \
  }

__global__ __launch_bounds__(256) void k_gemm1_mfma(const ushort_t* __restrict__ xh,
                                                    const ushort_t* __restrict__ xlo,
                                                    const ushort_t* __restrict__ whT,
                                                    const ushort_t* __restrict__ wlT,
                                                    const float* __restrict__ ba,
                                                    ushort_t* __restrict__ hs, ushort_t* __restrict__ t,
                                                    int N, int ntiles) {
  int bid = blockIdx.x;
  int g = bid / 24;
  int rem = bid - g * 24;
  int colblk = rem >> 3;              // 0..2
  int ytile = g * 8 + (rem & 7);
  if (ytile >= ntiles) return;

  int tid = threadIdx.x;
  int lane = tid & 63;
  int wave = tid >> 6;
  int wr = wave >> 1, wc = wave & 1;
  int rowbase = ytile * 128 + wr * 64;
  int gcb = colblk * 128 + wc * 64;        // global col base of this wave (0..383)
  int lr = lane & 15;
  int lk = (lane >> 4) * 8;
  int rq = (lane >> 4) * 4;

  int rows[4];
#pragma unroll
  for (int m = 0; m < 4; ++m) {
    int r = rowbase + m * 16 + lr;
    rows[m] = (r < N) ? r : (N - 1);   // clamp: loads valid, stores guarded
  }

  f32x4 acc[4][4] = {};
  bf16x8 ah[2][4], al[2][4], bh[2][4], bl[2][4];

  LOADK(0, ah[0], al[0], bh[0], bl[0]);
#pragma unroll
  for (int s = 0; s < 4; ++s) {
    int cur = s & 1, nxt = cur ^ 1;
    if (s < 3) LOADK(s + 1, ah[nxt], al[nxt], bh[nxt], bl[nxt]);
#pragma unroll
    for (int m = 0; m < 4; ++m)
#pragma unroll
      for (int n = 0; n < 4; ++n) {
        acc[m][n] = __builtin_amdgcn_mfma_f32_16x16x32_bf16(ah[cur][m], bl[cur][n], acc[m][n], 0, 0, 0);
        acc[m][n] = __builtin_amdgcn_mfma_f32_16x16x32_bf16(al[cur][m], bh[cur][n], acc[m][n], 0, 0, 0);
        acc[m][n] = __builtin_amdgcn_mfma_f32_16x16x32_bf16(ah[cur][m], bh[cur][n], acc[m][n], 0, 0, 0);
      }
  }

  if (colblk == 0) {
#pragma unroll
    for (int m = 0; m < 4; ++m)
#pragma unroll
      for (int i = 0; i < 4; ++i) {
        int row = rowbase + m * 16 + rq + i;
        if (row < N) {
#pragma unroll
          for (int n = 0; n < 4; ++n)
            hs[(size_t)row * DOUT + gcb + n * 16 + lr] = f2bf(acc[m][n][i]);
        }
      }
  } else {
    float bav[4];
#pragma unroll
    for (int n = 0; n < 4; ++n) bav[n] = ba[gcb - DOUT + n * 16 + lr];
#pragma unroll
    for (int m = 0; m < 4; ++m)
#pragma unroll
      for (int i = 0; i < 4; ++i) {
        int row = rowbase + m * 16 + rq + i;
        if (row < N) {
#pragma unroll
          for (int n = 0; n < 4; ++n)
            t[(size_t)row * TCOLS + gcb - DOUT + n * 16 + lr] =
                f2bf(fmaxf(acc[m][n][i] + bav[n], 0.f));
        }
      }
  }
}

// ---------------------------------------------------------------- VtZ + colsum, stage 1 (atomic-free)
__global__ __launch_bounds__(256) void k_red(const ushort_t* __restrict__ t, float* __restrict__ part,
                                             int N) {
  __shared__ float csh[512];
  int tid = threadIdx.x;
  int lane = tid & 63;
  int w = tid >> 6;            // wave 0..3 -> V-col strip w*16
  int lr = lane & 15;
  int lk = (lane >> 4) * 8;
  int vcol = 64 + w * 16 + lr; // t-col of A-operand (V region)
  int col2 = lane * 2;         // colsum col pair (0..127)

  f32x4 acc[4] = {};
  float cs0 = 0.f, cs1 = 0.f;
  int ntiles = (N + 31) >> 5;

  for (int tile = blockIdx.x; tile < ntiles; tile += gridDim.x) {
    int r0 = tile * 32;
    const ushort_t* base = &t[(size_t)r0 * TCOLS];
    bf16x8 a, b[4];
    if (r0 + 32 <= N) {
#pragma unroll
      for (int j = 0; j < 8; ++j)
        ((short*)&a)[j] = (short)base[(size_t)(lk + j) * TCOLS + vcol];
#pragma unroll
      for (int n = 0; n < 4; ++n)
#pragma unroll
        for (int j = 0; j < 8; ++j)
          ((short*)&b[n])[j] = (short)base[(size_t)(lk + j) * TCOLS + 128 + n * 16 + lr];
#pragma unroll
      for (int j = 0; j < 8; ++j) {
        ushort2 u = *(const ushort2*)&base[(size_t)(w * 8 + j) * TCOLS + col2];
        cs0 += bf2f(u.x); cs1 += bf2f(u.y);
      }
    } else {
#pragma unroll
      for (int j = 0; j < 8; ++j) {
        int r = r0 + lk + j;
        ((short*)&a)[j] = (r < N) ? (short)t[(size_t)r * TCOLS + vcol] : (short)0;
      }
#pragma unroll
      for (int n = 0; n < 4; ++n)
#pragma unroll
        for (int j = 0; j < 8; ++j) {
          int r = r0 + lk + j;
          ((short*)&b[n])[j] = (r < N) ? (short)t[(size_t)r * TCOLS + 128 + n * 16 + lr] : (short)0;
        }
#pragma unroll
      for (int j = 0; j < 8; ++j) {
        int r = r0 + w * 8 + j;
        if (r < N) {
          ushort2 u = *(const ushort2*)&t[(size_t)r * TCOLS + col2];
          cs0 += bf2f(u.x); cs1 += bf2f(u.y);
        }
      }
    }
#pragma unroll
    for (int n = 0; n < 4; ++n)
      acc[n] = __builtin_amdgcn_mfma_f32_16x16x32_bf16(a, b[n], acc[n], 0, 0, 0);
  }

  float* pb = &part[(size_t)blockIdx.x * PSTR];
  int rq = (lane >> 4) * 4;
#pragma unroll
  for (int n = 0; n < 4; ++n)
#pragma unroll
    for (int i = 0; i < 4; ++i)
      pb[(w * 16 + rq + i) * 64 + n * 16 + lr] = acc[n][i];

  csh[tid] = cs0;
  csh[256 + tid] = cs1;
  __syncthreads();
  if (w == 0) {
    float t0 = csh[lane] + csh[64 + lane] + csh[128 + lane] + csh[192 + lane];
    float t1 = csh[256 + lane] + csh[320 + lane] + csh[384 + lane] + csh[448 + lane];
    pb[4096 + col2] = t0;
    pb[4096 + col2 + 1] = t1;
  }
}

// ---------------------------------------------------------------- stage 2: sum P_RED partials
__global__ __launch_bounds__(256) void k_redsum(const float* __restrict__ part,
                                                float* __restrict__ VtZ, float* __restrict__ colsum) {
  __shared__ float s[256];
  int tid = threadIdx.x;
  int j = blockIdx.x * 64 + (tid & 63);
  int bc = tid >> 6;           // 0..3
  float a = 0.f;
#pragma unroll 4
  for (int b = bc; b < P_RED; b += 4) a += part[(size_t)b * PSTR + j];
  s[tid] = a;
  __syncthreads();
  if (bc == 0) {
    float v = s[tid] + s[tid + 64] + s[tid + 128] + s[tid + 192];
    if (j < 4096) VtZ[j] = v;
    else colsum[j - 4096] = v;
  }
}

// ---------------------------------------------------------------- D = N / dot(colsumU, colsumV)
__global__ __launch_bounds__(64) void k_d(const float* __restrict__ colsum, float* __restrict__ Dws, int N) {
  __shared__ float s[64];
  int k = threadIdx.x;
  s[k] = colsum[k] * colsum[64 + k];
  __syncthreads();
  for (int off = 32; off > 0; off >>= 1) {
    if (k < off) s[k] += s[k + off];
    __syncthreads();
  }
  if (k == 0) {
    float p = s[0];
    Dws[0] = (p != 0.f) ? ((float)N / p) : 0.f;
  }
}

// ---------------------------------------------------------------- Weff^T (K-major) build
__global__ __launch_bounds__(256) void k_prep(const float* __restrict__ VtZ,
                                              const float* __restrict__ Dws,
                                              const float* __restrict__ Wr,
                                              ushort_t* __restrict__ weffT) {
  int c = blockIdx.x;        // 0..127
  int k = threadIdx.x;       // 0..255
  float v;
  if (k < 128 || k >= 192) {
    v = Wr[(size_t)k * DOUT + c];
  } else {
    float Dv = Dws[0];
    int kk = k - 128;
    float acc = 0.f;
#pragma unroll 8
    for (int j = 0; j < 64; ++j)
      acc += VtZ[kk * 64 + j] * Wr[(size_t)(128 + j) * DOUT + c];
    v = acc * Dv;
  }
  weffT[(size_t)c * 256 + k] = f2bf(v);
}

// ---------------------------------------------------------------- out = [xl | U | T] @ Weff + br  (bf16 MFMA, fp32 out)
__global__ __launch_bounds__(256) void k_out_mfma(const ushort_t* __restrict__ xl,
                                                  const ushort_t* __restrict__ t,
                                                  const ushort_t* __restrict__ weffT,
                                                  const float* __restrict__ br,
                                                  float* __restrict__ out, int N) {
  int tid = threadIdx.x;
  int lane = tid & 63;
  int wave = tid >> 6;
  int wr = wave >> 1, wc = wave & 1;
  int rowbase = blockIdx.x * 128 + wr * 64;
  int cbase = wc * 64;
  int lr = lane & 15;
  int lk = (lane >> 4) * 8;

  int rows[4];
#pragma unroll
  for (int m = 0; m < 4; ++m) {
    int r = rowbase + m * 16 + lr;
    rows[m] = (r < N) ? r : (N - 1);
  }

  f32x4 acc[4][4] = {};

#pragma unroll
  for (int s = 0; s < 8; ++s) {
    int k0 = s * 32 + lk;
    bf16x8 a[4], b[4];
#pragma unroll
    for (int m = 0; m < 4; ++m) {
      const ushort_t* ap;
      if (s < 4)      ap = &xl[(size_t)rows[m] * DOUT + k0];
      else if (s < 6) ap = &t[(size_t)rows[m] * TCOLS + (k0 - 128)];
      else            ap = &t[(size_t)rows[m] * TCOLS + k0];
      a[m] = *(const bf16x8*)ap;
    }
#pragma unroll
    for (int n = 0; n < 4; ++n) {
      int c = cbase + n * 16 + lr;
      b[n] = *(const bf16x8*)&weffT[(size_t)c * 256 + k0];
    }
#pragma unroll
    for (int m = 0; m < 4; ++m)
#pragma unroll
      for (int n = 0; n < 4; ++n)
        acc[m][n] = __builtin_amdgcn_mfma_f32_16x16x32_bf16(a[m], b[n], acc[m][n], 0, 0, 0);
  }

  float brv[4];
#pragma unroll
  for (int n = 0; n < 4; ++n) brv[n] = br[cbase + n * 16 + lr];

  int rq = (lane >> 4) * 4;
#pragma unroll
  for (int m = 0; m < 4; ++m) {
#pragma unroll
    for (int i = 0; i < 4; ++i) {
      int row = rowbase + m * 16 + rq + i;
      if (row < N) {
#pragma unroll
        for (int n = 0; n < 4; ++n)
          out[(size_t)row * DOUT + cbase + n * 16 + lr] = acc[m][n][i] + brv[n];
      }
    }
  }
}

// ---------------------------------------------------------------- CSR gather-aggregate
__global__ __launch_bounds__(256) void k_aggn(const ushort_t* __restrict__ hs, const int2* __restrict__ csr,
                                              const int* __restrict__ offs, const float* __restrict__ dinv,
                                              const float* __restrict__ bg,
                                              ushort_t* __restrict__ xl, int N) {
  int node = blockIdx.x * 4 + (threadIdx.x >> 6);
  int lane = threadIdx.x & 63;
  if (node >= N) return;
  int c2 = 2 * lane;
  float dn = dinv[node];
  ushort2 u = *(const ushort2*)&hs[(size_t)node * DOUT + c2];
  float a0 = dn * dn * bf2f(u.x);
  float a1 = dn * dn * bf2f(u.y);
  int e = offs[node], e1 = offs[node + 1];
  for (; e + 4 <= e1; e += 4) {
    int2 q0 = csr[e], q1 = csr[e + 1], q2 = csr[e + 2], q3 = csr[e + 3];
    ushort2 r0 = *(const ushort2*)&hs[(size_t)q0.x * DOUT + c2];
    ushort2 r1 = *(const ushort2*)&hs[(size_t)q1.x * DOUT + c2];
    ushort2 r2 = *(const ushort2*)&hs[(size_t)q2.x * DOUT + c2];
    ushort2 r3 = *(const ushort2*)&hs[(size_t)q3.x * DOUT + c2];
    float n0 = __int_as_float(q0.y), n1 = __int_as_float(q1.y);
    float n2 = __int_as_float(q2.y), n3 = __int_as_float(q3.y);
    a0 += n0 * bf2f(r0.x) + n1 * bf2f(r1.x) + n2 * bf2f(r2.x) + n3 * bf2f(r3.x);
    a1 += n0 * bf2f(r0.y) + n1 * bf2f(r1.y) + n2 * bf2f(r2.y) + n3 * bf2f(r3.y);
  }
  for (; e < e1; ++e) {
    int2 q = csr[e];
    ushort2 r = *(const ushort2*)&hs[(size_t)q.x * DOUT + c2];
    float n0 = __int_as_float(q.y);
    a0 += n0 * bf2f(r.x);
    a1 += n0 * bf2f(r.y);
  }
  ushort2 o;
  o.x = f2bf(fmaxf(a0 + bg[c2], 0.f));
  o.y = f2bf(fmaxf(a1 + bg[c2 + 1], 0.f));
  *(ushort2*)&xl[(size_t)node * DOUT + c2] = o;
}

// ---------------------------------------------------------------- launch
extern "C" void kernel_launch(void* const* d_in, const int* in_sizes, int n_in,
                              void* d_out, int out_size, void* d_ws, size_t ws_size,
                              hipStream_t stream) {
  const float* x  = (const float*)d_in[0];
  const int* ei   = (const int*)d_in[1];
  const float* Wg = (const float*)d_in[2];
  const float* bg = (const float*)d_in[3];
  const float* Wa = (const float*)d_in[4];
  const float* ba = (const float*)d_in[5];
  const float* Wr = (const float*)d_in[6];
  const float* br = (const float*)d_in[7];
  float* out = (float*)d_out;     // fp32 output

  const int N = in_sizes[0] / DIN;
  const int E = in_sizes[1] / 2;

  char* p = (char*)d_ws;
  auto alloc = [&](size_t bytes) {
    char* r = p;
    p += (bytes + 255) & ~(size_t)255;
    return r;
  };
  float* Dws    = (float*)alloc(256);
  float* colsum = (float*)alloc(128 * 4);
  float* VtZ    = (float*)alloc(4096 * 4);
  int*   bsums  = (int*)alloc(1024);
  int*   boff   = (int*)alloc(1024);
  ushort_t* weffT = (ushort_t*)alloc(128 * 256 * 2);        // bf16 Weff^T (K-major)
  ushort_t* whT = (ushort_t*)alloc((size_t)WCOLS * DIN * 2);// bf16 [Wg|Wa]^T hi
  ushort_t* wlT = (ushort_t*)alloc((size_t)WCOLS * DIN * 2);// bf16 [Wg|Wa]^T lo
  float* part   = (float*)alloc((size_t)P_RED * PSTR * 4);  // stage-1 partials (16.5 MB)
  int*   degc   = (int*)alloc((size_t)N * 4);
  float* dinv   = (float*)alloc((size_t)N * 4);
  int*   offs   = (int*)alloc((size_t)(N + 1) * 4);
  int*   cursor = (int*)alloc((size_t)N * 4);
  int2*  csr    = (int2*)alloc((size_t)E * 8);              // (src, norm) per edge
  ushort_t* xh  = (ushort_t*)alloc((size_t)N * DIN * 2);    // bf16 x hi
  ushort_t* xlo = (ushort_t*)alloc((size_t)N * DIN * 2);    // bf16 x lo
  ushort_t* hs  = (ushort_t*)alloc((size_t)N * DOUT * 2);   // bf16 x@Wg
  ushort_t* t   = (ushort_t*)alloc((size_t)N * TCOLS * 2);  // bf16 relu(x@Wa+ba)
  ushort_t* xl  = (ushort_t*)alloc((size_t)N * DOUT * 2);   // bf16 x_local
  (void)ws_size; (void)n_in; (void)out_size;

  const int GN = (N + 255) / 256;
  const int GE = (E + 255) / 256;
  const int NBLK = (N + 1023) / 1024;   // <= 128 for N <= 131072
  const int NT128 = (N + 127) / 128;    // row tiles for gemm1
  const int G1 = ((NT128 + 7) / 8) * 24;  // swizzled 1-D grid (3 colblks x 8 tiles/group)
  const int shardN = (N + 7) / 8;

  k_init<<<GN, 256, 0, stream>>>(degc, VtZ, colsum, N);
  k_deg<<<GE, 256, 0, stream>>>(ei, degc, E);
  k_split<<<2048, 256, 0, stream>>>(x, xh, xlo, N * DIN / 4);
  k_wprep<<<WCOLS, 128, 0, stream>>>(Wg, Wa, whT, wlT);
  k_scan1<<<NBLK, 256, 0, stream>>>(degc, offs, bsums, N);
  k_scan2<<<1, 128, 0, stream>>>(bsums, boff, offs, NBLK, N);
  k_scan3<<<GN, 256, 0, stream>>>(offs, boff, degc, dinv, cursor, N);
  k_scatter<<<2048, 256, 0, stream>>>(ei, offs, cursor, dinv, csr, E, N, shardN);
  k_gemm1_mfma<<<G1, 256, 0, stream>>>(xh, xlo, whT, wlT, ba, hs, t, N, NT128);
  k_red<<<P_RED, 256, 0, stream>>>(t, part, N);
  k_redsum<<<PSTR / 64, 256, 0, stream>>>(part, VtZ, colsum);
  k_d<<<1, 64, 0, stream>>>(colsum, Dws, N);
  k_prep<<<128, 256, 0, stream>>>(VtZ, Dws, Wr, weffT);
  k_aggn<<<(N + 3) / 4, 256, 0, stream>>>(hs, csr, offs, dinv, bg, xl, N);
  k_out_mfma<<<(N + 127) / 128, 256, 0, stream>>>(xl, t, weffT, br, out, N);
}

// Round 7
// 478.299 us; speedup vs baseline: 1.0948x; 1.0948x over previous
//
#include <hip/hip_runtime.h>

// GCN + low-rank global attention (LRGA), N=100k, E=1.6M, D=128, K=64.
// R1: k_out -> bf16 MFMA with folded Weff.
// R2: k_gemm1 -> split-bf16 (hi/lo) MFMA 3-pass.
// R3: k_red -> atomic-free two-stage MFMA reduction.
// R4: FAILED (fused split / weight hoist). R5: reg dbuf = null.
// R6: scatter XCD-shard = null (WRITE still 64B/store); gemm1 swizzle cut FETCH 3x
//     but time flat -> VMEM-issue bound: every fragment load touched 16 lines.
// R7: fragment-order layouts. k_split/k_wprep emit data in MFMA per-lane order, so
//     each A/B fragment load is ONE coalesced 1KB burst (16x fewer line requests).
//     Scatter reverted to simple form.
#define DIN   128
#define DOUT  128
#define KR    64
#define TCOLS 256   // 4*K
#define WCOLS 384   // DOUT + TCOLS
#define P_RED 1024  // stage-1 partial blocks
#define PSTR  4224  // 4096 VtZ + 128 colsum

typedef unsigned short ushort_t;
typedef __attribute__((ext_vector_type(8))) short bf16x8;
typedef __attribute__((ext_vector_type(4))) float f32x4;

__device__ __forceinline__ float bf2f(unsigned short u) {
  return __uint_as_float(((unsigned int)u) << 16);
}
__device__ __forceinline__ unsigned short f2bf(float f) {
  unsigned int b = __float_as_uint(f);
  b = b + 0x7FFFu + ((b >> 16) & 1u);
  return (unsigned short)(b >> 16);
}

// ---------------------------------------------------------------- init
__global__ __launch_bounds__(256) void k_init(int* __restrict__ degc, float* __restrict__ VtZ,
                                              float* __restrict__ colsum, int N) {
  int i = blockIdx.x * 256 + threadIdx.x;
  if (i < N) degc[i] = 1;            // self-loop gives deg >= 1
  if (i < 4096) VtZ[i] = 0.f;
  if (i < 128) colsum[i] = 0.f;
}

// ---------------------------------------------------------------- degree (in-degree via dst row)
__global__ __launch_bounds__(256) void k_deg(const int* __restrict__ ei, int* __restrict__ degc, int E) {
  int e = blockIdx.x * 256 + threadIdx.x;
  if (e < E) atomicAdd(&degc[ei[E + e]], 1);
}

// ---------------------------------------------------------------- x -> bf16 hi/lo split, FRAGMENT ORDER.
// Fragment f = (r16, s): 16 rows x 32 k. Slot l (0..63): row = r16*16 + (l&15),
// k = s*32 + (l>>4)*8 (+j). Output offset = (f*64 + l)*8 -> writes fully coalesced.
__global__ __launch_bounds__(256) void k_split(const float* __restrict__ x,
                                               ushort_t* __restrict__ xhF, ushort_t* __restrict__ xloF,
                                               int N, int total_slots) {
  int gid = blockIdx.x * 256 + threadIdx.x;
  int stride = gridDim.x * 256;
  for (; gid < total_slots; gid += stride) {
    int f = gid >> 6, l = gid & 63;
    int r16 = f >> 2, s = f & 3;
    int row = r16 * 16 + (l & 15);
    int k = s * 32 + ((l >> 4) << 3);
    ushort4 h0, h1, l0, l1;
    if (row < N) {
      float4 a = *(const float4*)&x[(size_t)row * DIN + k];
      float4 b = *(const float4*)&x[(size_t)row * DIN + k + 4];
      h0.x = f2bf(a.x); h0.y = f2bf(a.y); h0.z = f2bf(a.z); h0.w = f2bf(a.w);
      h1.x = f2bf(b.x); h1.y = f2bf(b.y); h1.z = f2bf(b.z); h1.w = f2bf(b.w);
      l0.x = f2bf(a.x - bf2f(h0.x)); l0.y = f2bf(a.y - bf2f(h0.y));
      l0.z = f2bf(a.z - bf2f(h0.z)); l0.w = f2bf(a.w - bf2f(h0.w));
      l1.x = f2bf(b.x - bf2f(h1.x)); l1.y = f2bf(b.y - bf2f(h1.y));
      l1.z = f2bf(b.z - bf2f(h1.z)); l1.w = f2bf(b.w - bf2f(h1.w));
    } else {
      h0 = make_ushort4(0, 0, 0, 0); h1 = h0; l0 = h0; l1 = h0;
    }
    ((ushort4*)xhF)[gid * 2] = h0;
    ((ushort4*)xhF)[gid * 2 + 1] = h1;
    ((ushort4*)xloF)[gid * 2] = l0;
    ((ushort4*)xloF)[gid * 2 + 1] = l1;
  }
}

// ---------------------------------------------------------------- weights -> bf16 hi/lo, FRAGMENT ORDER.
// Fragment f = (c16, s): col = c16*16 + (l&15), k = s*32 + (l>>4)*8 (+j).
// 24 c16 * 4 s * 64 slots = 6144 slots -> grid 24 x 256.
__global__ __launch_bounds__(256) void k_wprep(const float* __restrict__ Wg, const float* __restrict__ Wa,
                                               ushort_t* __restrict__ whF, ushort_t* __restrict__ wlF) {
  int g = blockIdx.x * 256 + threadIdx.x;
  int f = g >> 6, l = g & 63;
  int c16 = f >> 2, s = f & 3;
  int col = c16 * 16 + (l & 15);
  int k = s * 32 + ((l >> 4) << 3);
#pragma unroll
  for (int j = 0; j < 8; ++j) {
    float v = (col < DOUT) ? Wg[(size_t)(k + j) * DOUT + col]
                           : Wa[(size_t)(k + j) * TCOLS + (col - DOUT)];
    ushort_t h = f2bf(v);
    whF[(size_t)g * 8 + j] = h;
    wlF[(size_t)g * 8 + j] = f2bf(v - bf2f(h));
  }
}

// ---------------------------------------------------------------- hierarchical scan, stage 1
__global__ __launch_bounds__(256) void k_scan1(const int* __restrict__ degc, int* __restrict__ offs,
                                               int* __restrict__ bsums, int N) {
  __shared__ int s[256];
  int tid = threadIdx.x;
  int base = blockIdx.x * 1024 + tid * 4;
  int c[4], e[4];
#pragma unroll
  for (int q = 0; q < 4; ++q) c[q] = (base + q < N) ? (degc[base + q] - 1) : 0;
  e[0] = 0; e[1] = c[0]; e[2] = e[1] + c[1]; e[3] = e[2] + c[2];
  int tsum = e[3] + c[3];
  s[tid] = tsum; __syncthreads();
  for (int off = 1; off < 256; off <<= 1) {
    int v = (tid >= off) ? s[tid - off] : 0;
    __syncthreads();
    s[tid] += v;
    __syncthreads();
  }
  int tb = s[tid] - tsum;
#pragma unroll
  for (int q = 0; q < 4; ++q) if (base + q < N) offs[base + q] = tb + e[q];
  if (tid == 255) bsums[blockIdx.x] = s[255];
}

// stage 2: exclusive scan of block sums (NBLK <= 128)
__global__ __launch_bounds__(128) void k_scan2(const int* __restrict__ bsums, int* __restrict__ boff,
                                               int* __restrict__ offs, int NBLK, int N) {
  __shared__ int s[128];
  int tid = threadIdx.x;
  int v = (tid < NBLK) ? bsums[tid] : 0;
  s[tid] = v; __syncthreads();
  for (int off = 1; off < 128; off <<= 1) {
    int u = (tid >= off) ? s[tid - off] : 0;
    __syncthreads();
    s[tid] += u;
    __syncthreads();
  }
  boff[tid] = s[tid] - v;
  if (tid == 127) offs[N] = s[127];   // total = E
}

// stage 3: add block offsets; dinv = rsqrt(deg); cursor = 0
__global__ __launch_bounds__(256) void k_scan3(int* __restrict__ offs, const int* __restrict__ boff,
                                               const int* __restrict__ degc, float* __restrict__ dinv,
                                               int* __restrict__ cursor, int N) {
  int i = blockIdx.x * 256 + threadIdx.x;
  if (i < N) {
    offs[i] += boff[i >> 10];
    dinv[i] = rsqrtf((float)degc[i]);
    cursor[i] = 0;
  }
}

// ---------------------------------------------------------------- CSR scatter (simple form)
__global__ __launch_bounds__(256) void k_scatter(const int* __restrict__ ei, const int* __restrict__ offs,
                                                 int* __restrict__ cursor, const float* __restrict__ dinv,
                                                 int2* __restrict__ csr, int E) {
  int e = blockIdx.x * 256 + threadIdx.x;
  if (e < E) {
    int s = ei[e];          // src
    int d = ei[E + e];      // dst
    int pos = atomicAdd(&cursor[d], 1);
    int2 q;
    q.x = s;
    q.y = __float_as_int(dinv[s] * dinv[d]);
    csr[offs[d] + pos] = q;
  }
}

// ---------------------------------------------------------------- fused GEMM via MFMA (split bf16, 3-pass)
// R7: all fragment loads are single coalesced 1KB bursts from fragment-order arrays.
#define LOADK(S, AH, AL, BH, BL)                                              \
  {                                                                           \
    _Pragma("unroll") for (int m_ = 0; m_ < 4; ++m_) {                        \
      size_t fo_ = (((size_t)(r16b + m_) * 4 + (S)) * 64 + lane) * 8;         \
      AH[m_] = *(const bf16x8*)&xhF[fo_];                                     \
      AL[m_] = *(const bf16x8*)&xloF[fo_];                                    \
    }                                                                         \
    _Pragma("unroll") for (int n_ = 0; n_ < 4; ++n_) {                        \
      size_t fo_ = (((size_t)(c16b + n_) * 4 + (S)) * 64 + lane) * 8;         \
      BH[n_] = *(const bf16x8*)&whF[fo_];                                     \
      BL[n_] = *(const bf16x8*)&wlF[fo_];                                     \
    }                                                                         \
  }

__global__ __launch_bounds__(256) void k_gemm1_mfma(const ushort_t* __restrict__ xhF,
                                                    const ushort_t* __restrict__ xloF,
                                                    const ushort_t* __restrict__ whF,
                                                    const ushort_t* __restrict__ wlF,
                                                    const float* __restrict__ ba,
                                                    ushort_t* __restrict__ hs, ushort_t* __restrict__ t,
                                                    int N, int ntiles) {
  int bid = blockIdx.x;
  int g = bid / 24;
  int rem = bid - g * 24;
  int colblk = rem >> 3;              // 0..2
  int ytile = g * 8 + (rem & 7);
  if (ytile >= ntiles) return;

  int tid = threadIdx.x;
  int lane = tid & 63;
  int wave = tid >> 6;
  int wr = wave >> 1, wc = wave & 1;
  int rowbase = ytile * 128 + wr * 64;
  int gcb = colblk * 128 + wc * 64;        // global col base of this wave (0..383)
  int r16b = ytile * 8 + wr * 4;           // A row-group base (16-row units)
  int c16b = colblk * 8 + wc * 4;          // B col-group base (16-col units)
  int lr = lane & 15;
  int rq = (lane >> 4) * 4;

  f32x4 acc[4][4] = {};
  bf16x8 ah[2][4], al[2][4], bh[2][4], bl[2][4];

  LOADK(0, ah[0], al[0], bh[0], bl[0]);
#pragma unroll
  for (int s = 0; s < 4; ++s) {
    int cur = s & 1, nxt = cur ^ 1;
    if (s < 3) LOADK(s + 1, ah[nxt], al[nxt], bh[nxt], bl[nxt]);
#pragma unroll
    for (int m = 0; m < 4; ++m)
#pragma unroll
      for (int n = 0; n < 4; ++n) {
        acc[m][n] = __builtin_amdgcn_mfma_f32_16x16x32_bf16(ah[cur][m], bl[cur][n], acc[m][n], 0, 0, 0);
        acc[m][n] = __builtin_amdgcn_mfma_f32_16x16x32_bf16(al[cur][m], bh[cur][n], acc[m][n], 0, 0, 0);
        acc[m][n] = __builtin_amdgcn_mfma_f32_16x16x32_bf16(ah[cur][m], bh[cur][n], acc[m][n], 0, 0, 0);
      }
  }

  if (colblk == 0) {
#pragma unroll
    for (int m = 0; m < 4; ++m)
#pragma unroll
      for (int i = 0; i < 4; ++i) {
        int row = rowbase + m * 16 + rq + i;
        if (row < N) {
#pragma unroll
          for (int n = 0; n < 4; ++n)
            hs[(size_t)row * DOUT + gcb + n * 16 + lr] = f2bf(acc[m][n][i]);
        }
      }
  } else {
    float bav[4];
#pragma unroll
    for (int n = 0; n < 4; ++n) bav[n] = ba[gcb - DOUT + n * 16 + lr];
#pragma unroll
    for (int m = 0; m < 4; ++m)
#pragma unroll
      for (int i = 0; i < 4; ++i) {
        int row = rowbase + m * 16 + rq + i;
        if (row < N) {
#pragma unroll
          for (int n = 0; n < 4; ++n)
            t[(size_t)row * TCOLS + gcb - DOUT + n * 16 + lr] =
                f2bf(fmaxf(acc[m][n][i] + bav[n], 0.f));
        }
      }
  }
}

// ---------------------------------------------------------------- VtZ + colsum, stage 1 (atomic-free)
__global__ __launch_bounds__(256) void k_red(const ushort_t* __restrict__ t, float* __restrict__ part,
                                             int N) {
  __shared__ float csh[512];
  int tid = threadIdx.x;
  int lane = tid & 63;
  int w = tid >> 6;            // wave 0..3 -> V-col strip w*16
  int lr = lane & 15;
  int lk = (lane >> 4) * 8;
  int vcol = 64 + w * 16 + lr; // t-col of A-operand (V region)
  int col2 = lane * 2;         // colsum col pair (0..127)

  f32x4 acc[4] = {};
  float cs0 = 0.f, cs1 = 0.f;
  int ntiles = (N + 31) >> 5;

  for (int tile = blockIdx.x; tile < ntiles; tile += gridDim.x) {
    int r0 = tile * 32;
    const ushort_t* base = &t[(size_t)r0 * TCOLS];
    bf16x8 a, b[4];
    if (r0 + 32 <= N) {
#pragma unroll
      for (int j = 0; j < 8; ++j)
        ((short*)&a)[j] = (short)base[(size_t)(lk + j) * TCOLS + vcol];
#pragma unroll
      for (int n = 0; n < 4; ++n)
#pragma unroll
        for (int j = 0; j < 8; ++j)
          ((short*)&b[n])[j] = (short)base[(size_t)(lk + j) * TCOLS + 128 + n * 16 + lr];
#pragma unroll
      for (int j = 0; j < 8; ++j) {
        ushort2 u = *(const ushort2*)&base[(size_t)(w * 8 + j) * TCOLS + col2];
        cs0 += bf2f(u.x); cs1 += bf2f(u.y);
      }
    } else {
#pragma unroll
      for (int j = 0; j < 8; ++j) {
        int r = r0 + lk + j;
        ((short*)&a)[j] = (r < N) ? (short)t[(size_t)r * TCOLS + vcol] : (short)0;
      }
#pragma unroll
      for (int n = 0; n < 4; ++n)
#pragma unroll
        for (int j = 0; j < 8; ++j) {
          int r = r0 + lk + j;
          ((short*)&b[n])[j] = (r < N) ? (short)t[(size_t)r * TCOLS + 128 + n * 16 + lr] : (short)0;
        }
#pragma unroll
      for (int j = 0; j < 8; ++j) {
        int r = r0 + w * 8 + j;
        if (r < N) {
          ushort2 u = *(const ushort2*)&t[(size_t)r * TCOLS + col2];
          cs0 += bf2f(u.x); cs1 += bf2f(u.y);
        }
      }
    }
#pragma unroll
    for (int n = 0; n < 4; ++n)
      acc[n] = __builtin_amdgcn_mfma_f32_16x16x32_bf16(a, b[n], acc[n], 0, 0, 0);
  }

  float* pb = &part[(size_t)blockIdx.x * PSTR];
  int rq = (lane >> 4) * 4;
#pragma unroll
  for (int n = 0; n < 4; ++n)
#pragma unroll
    for (int i = 0; i < 4; ++i)
      pb[(w * 16 + rq + i) * 64 + n * 16 + lr] = acc[n][i];

  csh[tid] = cs0;
  csh[256 + tid] = cs1;
  __syncthreads();
  if (w == 0) {
    float t0 = csh[lane] + csh[64 + lane] + csh[128 + lane] + csh[192 + lane];
    float t1 = csh[256 + lane] + csh[320 + lane] + csh[384 + lane] + csh[448 + lane];
    pb[4096 + col2] = t0;
    pb[4096 + col2 + 1] = t1;
  }
}

// ---------------------------------------------------------------- stage 2: sum P_RED partials
__global__ __launch_bounds__(256) void k_redsum(const float* __restrict__ part,
                                                float* __restrict__ VtZ, float* __restrict__ colsum) {
  __shared__ float s[256];
  int tid = threadIdx.x;
  int j = blockIdx.x * 64 + (tid & 63);
  int bc = tid >> 6;           // 0..3
  float a = 0.f;
#pragma unroll 4
  for (int b = bc; b < P_RED; b += 4) a += part[(size_t)b * PSTR + j];
  s[tid] = a;
  __syncthreads();
  if (bc == 0) {
    float v = s[tid] + s[tid + 64] + s[tid + 128] + s[tid + 192];
    if (j < 4096) VtZ[j] = v;
    else colsum[j - 4096] = v;
  }
}

// ---------------------------------------------------------------- D = N / dot(colsumU, colsumV)
__global__ __launch_bounds__(64) void k_d(const float* __restrict__ colsum, float* __restrict__ Dws, int N) {
  __shared__ float s[64];
  int k = threadIdx.x;
  s[k] = colsum[k] * colsum[64 + k];
  __syncthreads();
  for (int off = 32; off > 0; off >>= 1) {
    if (k < off) s[k] += s[k + off];
    __syncthreads();
  }
  if (k == 0) {
    float p = s[0];
    Dws[0] = (p != 0.f) ? ((float)N / p) : 0.f;
  }
}

// ---------------------------------------------------------------- Weff^T (K-major) build
__global__ __launch_bounds__(256) void k_prep(const float* __restrict__ VtZ,
                                              const float* __restrict__ Dws,
                                              const float* __restrict__ Wr,
                                              ushort_t* __restrict__ weffT) {
  int c = blockIdx.x;        // 0..127
  int k = threadIdx.x;       // 0..255
  float v;
  if (k < 128 || k >= 192) {
    v = Wr[(size_t)k * DOUT + c];
  } else {
    float Dv = Dws[0];
    int kk = k - 128;
    float acc = 0.f;
#pragma unroll 8
    for (int j = 0; j < 64; ++j)
      acc += VtZ[kk * 64 + j] * Wr[(size_t)(128 + j) * DOUT + c];
    v = acc * Dv;
  }
  weffT[(size_t)c * 256 + k] = f2bf(v);
}

// ---------------------------------------------------------------- out = [xl | U | T] @ Weff + br  (bf16 MFMA, fp32 out)
__global__ __launch_bounds__(256) void k_out_mfma(const ushort_t* __restrict__ xl,
                                                  const ushort_t* __restrict__ t,
                                                  const ushort_t* __restrict__ weffT,
                                                  const float* __restrict__ br,
                                                  float* __restrict__ out, int N) {
  int tid = threadIdx.x;
  int lane = tid & 63;
  int wave = tid >> 6;
  int wr = wave >> 1, wc = wave & 1;
  int rowbase = blockIdx.x * 128 + wr * 64;
  int cbase = wc * 64;
  int lr = lane & 15;
  int lk = (lane >> 4) * 8;

  int rows[4];
#pragma unroll
  for (int m = 0; m < 4; ++m) {
    int r = rowbase + m * 16 + lr;
    rows[m] = (r < N) ? r : (N - 1);
  }

  f32x4 acc[4][4] = {};

#pragma unroll
  for (int s = 0; s < 8; ++s) {
    int k0 = s * 32 + lk;
    bf16x8 a[4], b[4];
#pragma unroll
    for (int m = 0; m < 4; ++m) {
      const ushort_t* ap;
      if (s < 4)      ap = &xl[(size_t)rows[m] * DOUT + k0];
      else if (s < 6) ap = &t[(size_t)rows[m] * TCOLS + (k0 - 128)];
      else            ap = &t[(size_t)rows[m] * TCOLS + k0];
      a[m] = *(const bf16x8*)ap;
    }
#pragma unroll
    for (int n = 0; n < 4; ++n) {
      int c = cbase + n * 16 + lr;
      b[n] = *(const bf16x8*)&weffT[(size_t)c * 256 + k0];
    }
#pragma unroll
    for (int m = 0; m < 4; ++m)
#pragma unroll
      for (int n = 0; n < 4; ++n)
        acc[m][n] = __builtin_amdgcn_mfma_f32_16x16x32_bf16(a[m], b[n], acc[m][n], 0, 0, 0);
  }

  float brv[4];
#pragma unroll
  for (int n = 0; n < 4; ++n) brv[n] = br[cbase + n * 16 + lr];

  int rq = (lane >> 4) * 4;
#pragma unroll
  for (int m = 0; m < 4; ++m) {
#pragma unroll
    for (int i = 0; i < 4; ++i) {
      int row = rowbase + m * 16 + rq + i;
      if (row < N) {
#pragma unroll
        for (int n = 0; n < 4; ++n)
          out[(size_t)row * DOUT + cbase + n * 16 + lr] = acc[m][n][i] + brv[n];
      }
    }
  }
}

// ---------------------------------------------------------------- CSR gather-aggregate
__global__ __launch_bounds__(256) void k_aggn(const ushort_t* __restrict__ hs, const int2* __restrict__ csr,
                                              const int* __restrict__ offs, const float* __restrict__ dinv,
                                              const float* __restrict__ bg,
                                              ushort_t* __restrict__ xl, int N) {
  int node = blockIdx.x * 4 + (threadIdx.x >> 6);
  int lane = threadIdx.x & 63;
  if (node >= N) return;
  int c2 = 2 * lane;
  float dn = dinv[node];
  ushort2 u = *(const ushort2*)&hs[(size_t)node * DOUT + c2];
  float a0 = dn * dn * bf2f(u.x);
  float a1 = dn * dn * bf2f(u.y);
  int e = offs[node], e1 = offs[node + 1];
  for (; e + 4 <= e1; e += 4) {
    int2 q0 = csr[e], q1 = csr[e + 1], q2 = csr[e + 2], q3 = csr[e + 3];
    ushort2 r0 = *(const ushort2*)&hs[(size_t)q0.x * DOUT + c2];
    ushort2 r1 = *(const ushort2*)&hs[(size_t)q1.x * DOUT + c2];
    ushort2 r2 = *(const ushort2*)&hs[(size_t)q2.x * DOUT + c2];
    ushort2 r3 = *(const ushort2*)&hs[(size_t)q3.x * DOUT + c2];
    float n0 = __int_as_float(q0.y), n1 = __int_as_float(q1.y);
    float n2 = __int_as_float(q2.y), n3 = __int_as_float(q3.y);
    a0 += n0 * bf2f(r0.x) + n1 * bf2f(r1.x) + n2 * bf2f(r2.x) + n3 * bf2f(r3.x);
    a1 += n0 * bf2f(r0.y) + n1 * bf2f(r1.y) + n2 * bf2f(r2.y) + n3 * bf2f(r3.y);
  }
  for (; e < e1; ++e) {
    int2 q = csr[e];
    ushort2 r = *(const ushort2*)&hs[(size_t)q.x * DOUT + c2];
    float n0 = __int_as_float(q.y);
    a0 += n0 * bf2f(r.x);
    a1 += n0 * bf2f(r.y);
  }
  ushort2 o;
  o.x = f2bf(fmaxf(a0 + bg[c2], 0.f));
  o.y = f2bf(fmaxf(a1 + bg[c2 + 1], 0.f));
  *(ushort2*)&xl[(size_t)node * DOUT + c2] = o;
}

// ---------------------------------------------------------------- launch
extern "C" void kernel_launch(void* const* d_in, const int* in_sizes, int n_in,
                              void* d_out, int out_size, void* d_ws, size_t ws_size,
                              hipStream_t stream) {
  const float* x  = (const float*)d_in[0];
  const int* ei   = (const int*)d_in[1];
  const float* Wg = (const float*)d_in[2];
  const float* bg = (const float*)d_in[3];
  const float* Wa = (const float*)d_in[4];
  const float* ba = (const float*)d_in[5];
  const float* Wr = (const float*)d_in[6];
  const float* br = (const float*)d_in[7];
  float* out = (float*)d_out;     // fp32 output

  const int N = in_sizes[0] / DIN;
  const int E = in_sizes[1] / 2;

  const int NT128 = (N + 127) / 128;    // row tiles for gemm1
  const int N16P = NT128 * 8;           // padded 16-row groups
  const int NFRAG_A = N16P * 4;         // A fragments (1KB each)

  char* p = (char*)d_ws;
  auto alloc = [&](size_t bytes) {
    char* r = p;
    p += (bytes + 255) & ~(size_t)255;
    return r;
  };
  float* Dws    = (float*)alloc(256);
  float* colsum = (float*)alloc(128 * 4);
  float* VtZ    = (float*)alloc(4096 * 4);
  int*   bsums  = (int*)alloc(1024);
  int*   boff   = (int*)alloc(1024);
  ushort_t* weffT = (ushort_t*)alloc(128 * 256 * 2);        // bf16 Weff^T (K-major)
  ushort_t* whF = (ushort_t*)alloc((size_t)24 * 4 * 512 * 2); // weight frags hi (96KB)
  ushort_t* wlF = (ushort_t*)alloc((size_t)24 * 4 * 512 * 2); // weight frags lo
  float* part   = (float*)alloc((size_t)P_RED * PSTR * 4);  // stage-1 partials (16.5 MB)
  int*   degc   = (int*)alloc((size_t)N * 4);
  float* dinv   = (float*)alloc((size_t)N * 4);
  int*   offs   = (int*)alloc((size_t)(N + 1) * 4);
  int*   cursor = (int*)alloc((size_t)N * 4);
  int2*  csr    = (int2*)alloc((size_t)E * 8);              // (src, norm) per edge
  ushort_t* xhF = (ushort_t*)alloc((size_t)NFRAG_A * 512 * 2); // x frags hi (~25.6MB)
  ushort_t* xloF= (ushort_t*)alloc((size_t)NFRAG_A * 512 * 2); // x frags lo
  ushort_t* hs  = (ushort_t*)alloc((size_t)N * DOUT * 2);   // bf16 x@Wg
  ushort_t* t   = (ushort_t*)alloc((size_t)N * TCOLS * 2);  // bf16 relu(x@Wa+ba)
  ushort_t* xl  = (ushort_t*)alloc((size_t)N * DOUT * 2);   // bf16 x_local
  (void)ws_size; (void)n_in; (void)out_size;

  const int GN = (N + 255) / 256;
  const int GE = (E + 255) / 256;
  const int NBLK = (N + 1023) / 1024;   // <= 128 for N <= 131072
  const int G1 = ((NT128 + 7) / 8) * 24;  // swizzled 1-D grid (3 colblks x 8 tiles/group)

  k_init<<<GN, 256, 0, stream>>>(degc, VtZ, colsum, N);
  k_deg<<<GE, 256, 0, stream>>>(ei, degc, E);
  k_split<<<2048, 256, 0, stream>>>(x, xhF, xloF, N, NFRAG_A * 64);
  k_wprep<<<24, 256, 0, stream>>>(Wg, Wa, whF, wlF);
  k_scan1<<<NBLK, 256, 0, stream>>>(degc, offs, bsums, N);
  k_scan2<<<1, 128, 0, stream>>>(bsums, boff, offs, NBLK, N);
  k_scan3<<<GN, 256, 0, stream>>>(offs, boff, degc, dinv, cursor, N);
  k_scatter<<<GE, 256, 0, stream>>>(ei, offs, cursor, dinv, csr, E);
  k_gemm1_mfma<<<G1, 256, 0, stream>>>(xhF, xloF, whF, wlF, ba, hs, t, N, NT128);
  k_red<<<P_RED, 256, 0, stream>>>(t, part, N);
  k_redsum<<<PSTR / 64, 256, 0, stream>>>(part, VtZ, colsum);
  k_d<<<1, 64, 0, stream>>>(colsum, Dws, N);
  k_prep<<<128, 256, 0, stream>>>(VtZ, Dws, Wr, weffT);
  k_aggn<<<(N + 3) / 4, 256, 0, stream>>>(hs, csr, offs, dinv, bg, xl, N);
  k_out_mfma<<<(N + 127) / 128, 256, 0, stream>>>(xl, t, weffT, br, out, N);
}